// Round 1
// baseline (839.471 us; speedup 1.0000x reference)
//
#include <hip/hip_runtime.h>
#include <math.h>

// FFT long conv:  out = circconv_8193(x, f)/8193 + x*bias, masked by positions != -1
// Implemented as linear conv via FFT-16384 (radix-4, in-LDS), wrap-added:
//   y[n] = z[n] + z[n+8193],  z = ifft(FFT(x_pair) * G),
//   G = (FFT(f)/8193 + bias_d)/16384   (bias delta + all scaling folded into filter spectrum)
// Two batch rows packed as real+imag of one complex FFT (same real filter => no unpack).
// Forward DIF leaves scrambled order; G stored in the same scrambled order; inverse DIT
// consumes scrambled order and returns natural order. No bit-reversal pass.

namespace {

constexpr int Bb = 4, Hh = 16, Dd = 64, Ll = 8192;
constexpr int HD = Hh * Dd;          // 1024
constexpr int NFFT = 16384;
constexpr int NT = 1024;             // threads per block
constexpr float TH_STEP = 6.2831853071795864769e0f / 16384.0f;

__device__ inline float2 cmul(float2 a, float2 b) {
  return make_float2(a.x * b.x - a.y * b.y, a.x * b.y + a.y * b.x);
}
__device__ inline float2 cmulc(float2 a, float2 b) {  // a * conj(b)
  return make_float2(a.x * b.x + a.y * b.y, a.y * b.x - a.x * b.y);
}

// twiddle w^e, w = exp(-2*pi*i/16384), valid for e in [0, 12288)
// table tw[j] = w^j for j in [0, 2048]; r in (2048,4096) via w^r = (-i)*conj(w^(4096-r))
__device__ inline float2 twf(const float2* __restrict__ tw, int e) {
  int q4 = e >> 12;
  int r = e & 4095;
  float2 t;
  if (r <= 2048) {
    t = tw[r];
  } else {
    float2 v = tw[4096 - r];
    t = make_float2(-v.y, -v.x);
  }
  if (q4 == 1)      t = make_float2(t.y, -t.x);    // * (-i)
  else if (q4 == 2) t = make_float2(-t.x, -t.y);   // * (-1)
  return t;
}

__device__ inline void fill_tw(float2* tw, int tid) {
  for (int j = tid; j <= 2048; j += NT) {
    float sv, cv;
    sincosf(TH_STEP * (float)j, &sv, &cv);
    tw[j] = make_float2(cv, -sv);
  }
}

// Forward radix-4 DIF, natural input -> digit-reversed output, unscaled DFT.
__device__ inline void fft_dif(float2* a, const float2* __restrict__ tw, int tid) {
  for (int st = 0; st < 7; ++st) {
    int qsh = 12 - 2 * st;       // log2(quarter): 4096 .. 1
    int q = 1 << qsh;
#pragma unroll 4
    for (int bf = tid; bf < 4096; bf += NT) {
      int j = bf & (q - 1);
      int i0 = ((bf ^ j) << 2) | j;      // (bf-j)*4 + j
      float2 x0 = a[i0], x1 = a[i0 + q], x2 = a[i0 + 2 * q], x3 = a[i0 + 3 * q];
      float2 t0 = make_float2(x0.x + x2.x, x0.y + x2.y);
      float2 t1 = make_float2(x0.x - x2.x, x0.y - x2.y);
      float2 t2 = make_float2(x1.x + x3.x, x1.y + x3.y);
      float2 t3 = make_float2(x1.x - x3.x, x1.y - x3.y);
      float2 y0 = make_float2(t0.x + t2.x, t0.y + t2.y);
      float2 y2 = make_float2(t0.x - t2.x, t0.y - t2.y);
      float2 mit3 = make_float2(t3.y, -t3.x);             // -i * t3
      float2 y1 = make_float2(t1.x + mit3.x, t1.y + mit3.y);
      float2 y3 = make_float2(t1.x - mit3.x, t1.y - mit3.y);
      int e1 = j << (2 * st);
      y1 = cmul(y1, twf(tw, e1));
      y2 = cmul(y2, twf(tw, 2 * e1));
      y3 = cmul(y3, twf(tw, 3 * e1));
      a[i0] = y0; a[i0 + q] = y1; a[i0 + 2 * q] = y2; a[i0 + 3 * q] = y3;
    }
    __syncthreads();
  }
}

// Inverse: runs the DIF stages backward (DIT form), digit-reversed input -> natural
// output. Unscaled (factor 16384 vs true ifft; folded into G).
__device__ inline void fft_dit_inv(float2* a, const float2* __restrict__ tw, int tid) {
  for (int st = 6; st >= 0; --st) {
    int qsh = 12 - 2 * st;
    int q = 1 << qsh;
#pragma unroll 4
    for (int bf = tid; bf < 4096; bf += NT) {
      int j = bf & (q - 1);
      int i0 = ((bf ^ j) << 2) | j;
      int e1 = j << (2 * st);
      float2 u0 = a[i0];
      float2 u1 = cmulc(a[i0 + q],     twf(tw, e1));
      float2 u2 = cmulc(a[i0 + 2 * q], twf(tw, 2 * e1));
      float2 u3 = cmulc(a[i0 + 3 * q], twf(tw, 3 * e1));
      float2 t0 = make_float2(u0.x + u2.x, u0.y + u2.y);
      float2 t1 = make_float2(u0.x - u2.x, u0.y - u2.y);
      float2 t2 = make_float2(u1.x + u3.x, u1.y + u3.y);
      float2 t3 = make_float2(u1.x - u3.x, u1.y - u3.y);
      float2 it3 = make_float2(-t3.y, t3.x);              // +i * t3
      a[i0]         = make_float2(t0.x + t2.x, t0.y + t2.y);
      a[i0 + q]     = make_float2(t1.x + it3.x, t1.y + it3.y);
      a[i0 + 2 * q] = make_float2(t0.x - t2.x, t0.y - t2.y);
      a[i0 + 3 * q] = make_float2(t1.x - it3.x, t1.y - it3.y);
    }
    __syncthreads();
  }
}

}  // namespace

// Kernel A: per (h,d) row, G = (FFT_16384(f)/8193 + bias_d)/16384, scrambled order.
__global__ __launch_bounds__(NT) void filt_fft_kernel(const float* __restrict__ filters,
                                                      const float* __restrict__ bias,
                                                      float2* __restrict__ G) {
  __shared__ float2 a[NFFT];
  __shared__ float2 tw[2064];
  int tid = threadIdx.x;
  int hd = blockIdx.x;
  int d = hd & (Dd - 1);
  fill_tw(tw, tid);
  const float scale = 1.0f / (8193.0f * 16384.0f);
  const float2* f2 = reinterpret_cast<const float2*>(filters + (size_t)hd * Ll);
  for (int n2 = tid; n2 < Ll / 2; n2 += NT) {
    float2 v = f2[n2];
    a[2 * n2]     = make_float2(v.x * scale, 0.0f);
    a[2 * n2 + 1] = make_float2(v.y * scale, 0.0f);
  }
  for (int n = Ll + tid; n < NFFT; n += NT) a[n] = make_float2(0.0f, 0.0f);
  __syncthreads();
  fft_dif(a, tw, tid);
  float bd = bias[d] * (1.0f / 16384.0f);   // delta-spectrum: constant over all bins
  float4* g4 = reinterpret_cast<float4*>(G + (size_t)hd * NFFT);
  for (int p = tid; p < NFFT / 2; p += NT) {
    float2 a0 = a[2 * p], a1 = a[2 * p + 1];
    g4[p] = make_float4(a0.x + bd, a0.y, a1.x + bd, a1.y);
  }
}

// Kernel B: per (batch-pair, h, d): pack 2 rows, FFT, *G, IFFT, wrap-add, mask, store.
__global__ __launch_bounds__(NT) void conv_fft_kernel(const float* __restrict__ inputs,
                                                      const float2* __restrict__ G,
                                                      const int* __restrict__ positions,
                                                      float* __restrict__ out) {
  __shared__ float2 a[NFFT];
  __shared__ float2 tw[2064];
  int tid = threadIdx.x;
  int blk = blockIdx.x;              // pair*1024 + hd
  int hd = blk & (HD - 1);
  int pair = blk >> 10;
  int b0 = 2 * pair, b1 = b0 + 1;
  fill_tw(tw, tid);
  const float2* x0 = reinterpret_cast<const float2*>(inputs + ((size_t)b0 * HD + hd) * Ll);
  const float2* x1 = reinterpret_cast<const float2*>(inputs + ((size_t)b1 * HD + hd) * Ll);
  for (int n2 = tid; n2 < Ll / 2; n2 += NT) {
    float2 v0 = x0[n2];
    float2 v1 = x1[n2];
    a[2 * n2]     = make_float2(v0.x, v1.x);
    a[2 * n2 + 1] = make_float2(v0.y, v1.y);
  }
  for (int n = Ll + tid; n < NFFT; n += NT) a[n] = make_float2(0.0f, 0.0f);
  __syncthreads();
  fft_dif(a, tw, tid);
  // pointwise multiply in scrambled order (same permutation as kernel A's output)
  const float4* g4 = reinterpret_cast<const float4*>(G + (size_t)hd * NFFT);
  for (int p = tid; p < NFFT / 2; p += NT) {
    float4 gg = g4[p];
    a[2 * p]     = cmul(a[2 * p],     make_float2(gg.x, gg.y));
    a[2 * p + 1] = cmul(a[2 * p + 1], make_float2(gg.z, gg.w));
  }
  __syncthreads();
  fft_dit_inv(a, tw, tid);
  // epilogue: y[n] = z[n] + z[n+8193]; real->b0 row, imag->b1 row; mask; store
  const int2* pos0 = reinterpret_cast<const int2*>(positions + (size_t)b0 * Ll);
  const int2* pos1 = reinterpret_cast<const int2*>(positions + (size_t)b1 * Ll);
  float2* o0 = reinterpret_cast<float2*>(out + ((size_t)b0 * HD + hd) * Ll);
  float2* o1 = reinterpret_cast<float2*>(out + ((size_t)b1 * HD + hd) * Ll);
  for (int n2 = tid; n2 < Ll / 2; n2 += NT) {
    int n = 2 * n2;
    float2 wA = a[n], wB = a[n + 1];
    float2 vA = a[n + 8193];                       // n <= 8190 always here
    float2 vB = (n2 < Ll / 2 - 1) ? a[n + 8194] : make_float2(0.0f, 0.0f);
    int2 p0 = pos0[n2];
    int2 p1 = pos1[n2];
    float2 r0 = make_float2(wA.x + vA.x, wB.x + vB.x);
    float2 r1 = make_float2(wA.y + vA.y, wB.y + vB.y);
    r0.x = (p0.x != -1) ? r0.x : 0.0f;
    r0.y = (p0.y != -1) ? r0.y : 0.0f;
    r1.x = (p1.x != -1) ? r1.x : 0.0f;
    r1.y = (p1.y != -1) ? r1.y : 0.0f;
    o0[n2] = r0;
    o1[n2] = r1;
  }
}

extern "C" void kernel_launch(void* const* d_in, const int* in_sizes, int n_in,
                              void* d_out, int out_size, void* d_ws, size_t ws_size,
                              hipStream_t stream) {
  const float* inputs    = (const float*)d_in[0];   // (B,H,D,L) fp32
  const float* filters   = (const float*)d_in[1];   // (H,D,L) fp32
  const float* bias      = (const float*)d_in[2];   // (D,) fp32
  const int*   positions = (const int*)d_in[3];     // (B,L) int32
  float* outp = (float*)d_out;                      // (B,H,D,L) fp32
  float2* G = (float2*)d_ws;                        // HD * 16384 complex = 128 MiB

  hipLaunchKernelGGL(filt_fft_kernel, dim3(HD), dim3(NT), 0, stream, filters, bias, G);
  hipLaunchKernelGGL(conv_fft_kernel, dim3(HD * 2), dim3(NT), 0, stream,
                     inputs, G, positions, outp);
}

// Round 3
// 490.406 us; speedup vs baseline: 1.7118x; 1.7118x over previous
//
#include <hip/hip_runtime.h>
#include <math.h>

// FFT long conv:  out = circconv_8193(x, h)/8193 masked, where h = f + 8193*bias_d*delta.
// Linear conv via FFT-16384 (radix-4, in-LDS), wrap-added: y[n] = z[n] + z[n+8193].
// Two batch rows packed as real+imag of one complex FFT (same real filter => no unpack).
// DIF forward (natural->scrambled), pointwise *G in scrambled order, DIT inverse
// (scrambled->natural). No bit-reversal pass, no twiddle table (v_sin/v_cos, first
// quadrant only), LDS padded every 16 complex (PIDX) => conflict-floor for all strides.
// Fusions: load+stage0; stage6+G-mul+inv-stage6 (all unity twiddles, quad-local);
// kernel A: stage6 fused with G store (registers->global).

namespace {

constexpr int Hh = 16, Dd = 64, Ll = 8192;
constexpr int HD = Hh * Dd;          // 1024
constexpr int NFFT = 16384;
constexpr int NT = 1024;             // threads per block
constexpr int NPAD = NFFT + (NFFT >> 4);   // 17408 float2 = 139264 B LDS

#define PIDX(i) ((i) + ((i) >> 4))

__device__ inline float2 cmul(float2 a, float2 b) {
  return make_float2(a.x * b.x - a.y * b.y, a.x * b.y + a.y * b.x);
}
__device__ inline float2 cmulc(float2 a, float2 b) {  // a * conj(b)
  return make_float2(a.x * b.x + a.y * b.y, a.y * b.x - a.x * b.y);
}

// w^e = exp(-2*pi*i*e/16384), e in [0,4096)  (first quadrant; revolutions input)
__device__ inline float2 twgen(int e) {
  float x = (float)e * (1.0f / 16384.0f);
  return make_float2(__builtin_amdgcn_cosf(x), -__builtin_amdgcn_sinf(x));
}

// Forward DIF stages st=1..5 (stage 0 and 6 are fused at call sites).
__device__ inline void fft_dif_mid(float2* a, int tid) {
#pragma unroll
  for (int st = 1; st <= 5; ++st) {
    const int q = 1 << (12 - 2 * st);
#pragma unroll 4
    for (int bf = tid; bf < 4096; bf += NT) {
      int j = bf & (q - 1);
      int i0 = ((bf ^ j) << 2) | j;
      int p0 = PIDX(i0), p1 = PIDX(i0 + q), p2 = PIDX(i0 + 2 * q), p3 = PIDX(i0 + 3 * q);
      float2 x0 = a[p0], x1 = a[p1], x2 = a[p2], x3 = a[p3];
      float2 t0 = make_float2(x0.x + x2.x, x0.y + x2.y);
      float2 t1 = make_float2(x0.x - x2.x, x0.y - x2.y);
      float2 t2 = make_float2(x1.x + x3.x, x1.y + x3.y);
      float2 t3 = make_float2(x1.x - x3.x, x1.y - x3.y);
      float2 y0 = make_float2(t0.x + t2.x, t0.y + t2.y);
      float2 y2 = make_float2(t0.x - t2.x, t0.y - t2.y);
      float2 y1 = make_float2(t1.x + t3.y, t1.y - t3.x);   // t1 + (-i)t3
      float2 y3 = make_float2(t1.x - t3.y, t1.y + t3.x);   // t1 - (-i)t3
      float2 w1 = twgen(j << (2 * st));
      float2 w2 = cmul(w1, w1);
      float2 w3 = cmul(w2, w1);
      a[p0] = y0;
      a[p1] = cmul(y1, w1);
      a[p2] = cmul(y2, w2);
      a[p3] = cmul(y3, w3);
    }
    __syncthreads();
  }
}

// Inverse DIT stages st=5..0 (stage 6 fused with G-multiply at call site).
__device__ inline void fft_dit_mid(float2* a, int tid) {
#pragma unroll
  for (int st = 5; st >= 0; --st) {
    const int q = 1 << (12 - 2 * st);
#pragma unroll 4
    for (int bf = tid; bf < 4096; bf += NT) {
      int j = bf & (q - 1);
      int i0 = ((bf ^ j) << 2) | j;
      int p0 = PIDX(i0), p1 = PIDX(i0 + q), p2 = PIDX(i0 + 2 * q), p3 = PIDX(i0 + 3 * q);
      float2 w1 = twgen(j << (2 * st));
      float2 w2 = cmul(w1, w1);
      float2 w3 = cmul(w2, w1);
      float2 u0 = a[p0];
      float2 u1 = cmulc(a[p1], w1);
      float2 u2 = cmulc(a[p2], w2);
      float2 u3 = cmulc(a[p3], w3);
      float2 t0 = make_float2(u0.x + u2.x, u0.y + u2.y);
      float2 t1 = make_float2(u0.x - u2.x, u0.y - u2.y);
      float2 t2 = make_float2(u1.x + u3.x, u1.y + u3.y);
      float2 t3 = make_float2(u1.x - u3.x, u1.y - u3.y);
      a[p0] = make_float2(t0.x + t2.x, t0.y + t2.y);
      a[p1] = make_float2(t1.x - t3.y, t1.y + t3.x);       // t1 + i*t3
      a[p2] = make_float2(t0.x - t2.x, t0.y - t2.y);
      a[p3] = make_float2(t1.x + t3.y, t1.y - t3.x);       // t1 - i*t3
    }
    __syncthreads();
  }
}

}  // namespace

// Kernel A: per (h,d) row, G = (FFT_16384(h)/8193)/16384 in scrambled order,
// h = filter + 8193*bias_d*delta (delta spectrum = constant over bins).
__global__ __launch_bounds__(NT) void filt_fft_kernel(const float* __restrict__ filters,
                                                      const float* __restrict__ bias,
                                                      float2* __restrict__ G) {
  __shared__ float2 a[NPAD];
  int tid = threadIdx.x;
  int hd = blockIdx.x;
  int d = hd & (Dd - 1);
  const float sc = 1.0f / (8193.0f * 16384.0f);
  const float* f = filters + (size_t)hd * Ll;
  // fused: load (real, zero-padded: x2=x3=0) + forward stage 0 (q=4096)
#pragma unroll 4
  for (int bf = tid; bf < 4096; bf += NT) {
    float f0 = f[bf] * sc;
    float f1 = f[bf + 4096] * sc;
    float2 y0 = make_float2(f0 + f1, 0.0f);
    float2 y2 = make_float2(f0 - f1, 0.0f);
    float2 y1 = make_float2(f0, -f1);                      // f0 - i*f1
    float2 y3 = make_float2(f0, f1);                       // f0 + i*f1
    float2 w1 = twgen(bf);
    float2 w2 = cmul(w1, w1);
    float2 w3 = cmul(w2, w1);
    a[PIDX(bf)] = y0;
    a[PIDX(bf + 4096)]  = cmul(y1, w1);
    a[PIDX(bf + 8192)]  = cmul(y2, w2);
    a[PIDX(bf + 12288)] = cmul(y3, w3);
  }
  __syncthreads();
  fft_dif_mid(a, tid);
  // fused: forward stage 6 (q=1, unity twiddles) + bias add + G store from registers
  float bd = bias[d] * (1.0f / 16384.0f);
  float4* g4 = reinterpret_cast<float4*>(G + (size_t)hd * NFFT);
#pragma unroll 4
  for (int bf = tid; bf < 4096; bf += NT) {
    int i0 = bf << 2;
    float2 x0 = a[PIDX(i0)], x1 = a[PIDX(i0 + 1)], x2 = a[PIDX(i0 + 2)], x3 = a[PIDX(i0 + 3)];
    float2 t0 = make_float2(x0.x + x2.x, x0.y + x2.y);
    float2 t1 = make_float2(x0.x - x2.x, x0.y - x2.y);
    float2 t2 = make_float2(x1.x + x3.x, x1.y + x3.y);
    float2 t3 = make_float2(x1.x - x3.x, x1.y - x3.y);
    float2 y0 = make_float2(t0.x + t2.x, t0.y + t2.y);
    float2 y2 = make_float2(t0.x - t2.x, t0.y - t2.y);
    float2 y1 = make_float2(t1.x + t3.y, t1.y - t3.x);
    float2 y3 = make_float2(t1.x - t3.y, t1.y + t3.x);
    g4[2 * bf]     = make_float4(y0.x + bd, y0.y, y1.x + bd, y1.y);
    g4[2 * bf + 1] = make_float4(y2.x + bd, y2.y, y3.x + bd, y3.y);
  }
}

// Kernel B: per (batch-pair, h, d): pack 2 rows, FFT, *G, IFFT, wrap-add, mask, store.
__global__ __launch_bounds__(NT) void conv_fft_kernel(const float* __restrict__ inputs,
                                                      const float2* __restrict__ G,
                                                      const int* __restrict__ positions,
                                                      float* __restrict__ out) {
  __shared__ float2 a[NPAD];
  int tid = threadIdx.x;
  int blk = blockIdx.x;              // pair*1024 + hd
  int hd = blk & (HD - 1);
  int pair = blk >> 10;
  int b0 = 2 * pair, b1 = b0 + 1;
  const float* r0 = inputs + ((size_t)b0 * HD + hd) * Ll;
  const float* r1 = inputs + ((size_t)b1 * HD + hd) * Ll;
  // fused: load (packed complex, zero-padded: x2=x3=0) + forward stage 0 (q=4096)
#pragma unroll 4
  for (int bf = tid; bf < 4096; bf += NT) {
    float2 x0 = make_float2(r0[bf], r1[bf]);
    float2 x1 = make_float2(r0[bf + 4096], r1[bf + 4096]);
    float2 y0 = make_float2(x0.x + x1.x, x0.y + x1.y);
    float2 y2 = make_float2(x0.x - x1.x, x0.y - x1.y);
    float2 y1 = make_float2(x0.x + x1.y, x0.y - x1.x);     // x0 - i*x1
    float2 y3 = make_float2(x0.x - x1.y, x0.y + x1.x);     // x0 + i*x1
    float2 w1 = twgen(bf);
    float2 w2 = cmul(w1, w1);
    float2 w3 = cmul(w2, w1);
    a[PIDX(bf)] = y0;
    a[PIDX(bf + 4096)]  = cmul(y1, w1);
    a[PIDX(bf + 8192)]  = cmul(y2, w2);
    a[PIDX(bf + 12288)] = cmul(y3, w3);
  }
  __syncthreads();
  fft_dif_mid(a, tid);
  // fused: forward stage 6 + G multiply + inverse stage 6 (q=1, all unity twiddles)
  const float4* g4 = reinterpret_cast<const float4*>(G + (size_t)hd * NFFT);
#pragma unroll 4
  for (int bf = tid; bf < 4096; bf += NT) {
    int i0 = bf << 2;
    int p0 = PIDX(i0), p1 = PIDX(i0 + 1), p2 = PIDX(i0 + 2), p3 = PIDX(i0 + 3);
    float2 x0 = a[p0], x1 = a[p1], x2 = a[p2], x3 = a[p3];
    float2 t0 = make_float2(x0.x + x2.x, x0.y + x2.y);
    float2 t1 = make_float2(x0.x - x2.x, x0.y - x2.y);
    float2 t2 = make_float2(x1.x + x3.x, x1.y + x3.y);
    float2 t3 = make_float2(x1.x - x3.x, x1.y - x3.y);
    float2 y0 = make_float2(t0.x + t2.x, t0.y + t2.y);
    float2 y2 = make_float2(t0.x - t2.x, t0.y - t2.y);
    float2 y1 = make_float2(t1.x + t3.y, t1.y - t3.x);
    float2 y3 = make_float2(t1.x - t3.y, t1.y + t3.x);
    float4 ga = g4[2 * bf];
    float4 gb = g4[2 * bf + 1];
    float2 u0 = cmul(y0, make_float2(ga.x, ga.y));
    float2 u1 = cmul(y1, make_float2(ga.z, ga.w));
    float2 u2 = cmul(y2, make_float2(gb.x, gb.y));
    float2 u3 = cmul(y3, make_float2(gb.z, gb.w));
    float2 s0 = make_float2(u0.x + u2.x, u0.y + u2.y);
    float2 s1 = make_float2(u0.x - u2.x, u0.y - u2.y);
    float2 s2 = make_float2(u1.x + u3.x, u1.y + u3.y);
    float2 s3 = make_float2(u1.x - u3.x, u1.y - u3.y);
    a[p0] = make_float2(s0.x + s2.x, s0.y + s2.y);
    a[p1] = make_float2(s1.x - s3.y, s1.y + s3.x);         // s1 + i*s3
    a[p2] = make_float2(s0.x - s2.x, s0.y - s2.y);
    a[p3] = make_float2(s1.x + s3.y, s1.y - s3.x);         // s1 - i*s3
  }
  __syncthreads();
  fft_dit_mid(a, tid);
  // epilogue: y[n] = z[n] + z[n+8193]; real->b0 row, imag->b1 row; mask; store
  const int2* pos0 = reinterpret_cast<const int2*>(positions + (size_t)b0 * Ll);
  const int2* pos1 = reinterpret_cast<const int2*>(positions + (size_t)b1 * Ll);
  float2* o0 = reinterpret_cast<float2*>(out + ((size_t)b0 * HD + hd) * Ll);
  float2* o1 = reinterpret_cast<float2*>(out + ((size_t)b1 * HD + hd) * Ll);
#pragma unroll 4
  for (int n2 = tid; n2 < Ll / 2; n2 += NT) {
    int n = 2 * n2;
    float2 wA = a[PIDX(n)], wB = a[PIDX(n + 1)];
    float2 vA = a[PIDX(n + 8193)];
    float2 vB = (n2 < Ll / 2 - 1) ? a[PIDX(n + 8194)] : make_float2(0.0f, 0.0f);
    int2 p0 = pos0[n2];
    int2 p1 = pos1[n2];
    float2 rr0 = make_float2(wA.x + vA.x, wB.x + vB.x);
    float2 rr1 = make_float2(wA.y + vA.y, wB.y + vB.y);
    rr0.x = (p0.x != -1) ? rr0.x : 0.0f;
    rr0.y = (p0.y != -1) ? rr0.y : 0.0f;
    rr1.x = (p1.x != -1) ? rr1.x : 0.0f;
    rr1.y = (p1.y != -1) ? rr1.y : 0.0f;
    o0[n2] = rr0;
    o1[n2] = rr1;
  }
}

extern "C" void kernel_launch(void* const* d_in, const int* in_sizes, int n_in,
                              void* d_out, int out_size, void* d_ws, size_t ws_size,
                              hipStream_t stream) {
  const float* inputs    = (const float*)d_in[0];   // (B,H,D,L) fp32
  const float* filters   = (const float*)d_in[1];   // (H,D,L) fp32
  const float* bias      = (const float*)d_in[2];   // (D,) fp32
  const int*   positions = (const int*)d_in[3];     // (B,L) int32
  float* outp = (float*)d_out;                      // (B,H,D,L) fp32
  float2* G = (float2*)d_ws;                        // HD * 16384 complex = 128 MiB

  hipLaunchKernelGGL(filt_fft_kernel, dim3(HD), dim3(NT), 0, stream, filters, bias, G);
  hipLaunchKernelGGL(conv_fft_kernel, dim3(HD * 2), dim3(NT), 0, stream,
                     inputs, G, positions, outp);
}